// Round 4
// baseline (252.733 us; speedup 1.0000x reference)
//
#include <hip/hip_runtime.h>
#include <hip/hip_cooperative_groups.h>
#include <stdint.h>

namespace cg = cooperative_groups;

#define D      10000
#define WPR    313              // ceil(10000/32) words per hypervector row
#define NPIX   784
#define NB     64
#define NC     10
#define NPC    16               // p-chunks
#define PCL    49               // pixels per chunk (16*49=784), 6-bit counters
#define NROWS  (256 + NPIX)     // 1040 rows to pack
#define GRID   512              // 2 blocks/CU worst case -> coop check cannot fail
#define BLK    256
#define NT2    (NB * NPC * 5)   // 5120 count wave-tasks (5 word-groups of 64)

// ---- phase 1 helper: pack sign bits of one 32-float word (bit=1 <=> v<0) ----
__device__ __forceinline__ void pack_task(int task, const float* __restrict__ lev,
                                          const float* __restrict__ pos,
                                          uint32_t* __restrict__ Lp,
                                          uint32_t* __restrict__ Pp) {
    int row = task / WPR;
    int w   = task - row * WPR;
    const float* src; uint32_t* dst;
    if (row < 256) { src = lev + (size_t)row * D;         dst = Lp + row * WPR; }
    else           { src = pos + (size_t)(row - 256) * D; dst = Pp + (row - 256) * WPR; }
    const uint4* p4 = (const uint4*)(src + w * 32);
    uint32_t word = 0;
    int kmax = (w < WPR - 1) ? 8 : 4;          // last word: 16 valid floats
    for (int k = 0; k < kmax; ++k) {
        uint4 u = p4[k];
        word |= (u.x >> 31) << (4*k)     | (u.y >> 31) << (4*k + 1)
              | (u.z >> 31) << (4*k + 2) | (u.w >> 31) << (4*k + 3);
    }
    dst[w] = word;
}

// ---- phase 2 helper: one (b, pc, word) bit-sliced popcount task -------------
// vidx: lane i (i<49) holds level-row offset (idx*WPR) of pixel pc*49+i.
__device__ __forceinline__ void count_task(int b, int pc, int w, int vidx,
                                           const uint32_t* __restrict__ Lp,
                                           const uint32_t* __restrict__ Pp,
                                           uint32_t* __restrict__ partial) {
    if (w >= WPR) return;
    uint32_t s0 = 0, s1 = 0, s2 = 0, s3 = 0, s4 = 0, s5 = 0;
    const uint32_t* pp = Pp + (pc * PCL) * WPR + w;
    #pragma unroll
    for (int i = 0; i < PCL; ++i) {
        int ro = __builtin_amdgcn_readlane(vidx, i);   // wave-uniform row offset
        uint32_t c = Lp[ro + w] ^ pp[i * WPR];
        uint32_t t;
        t = s0 & c; s0 ^= c; c = t;
        t = s1 & c; s1 ^= c; c = t;
        t = s2 & c; s2 ^= c; c = t;
        t = s3 & c; s3 ^= c; c = t;
        t = s4 & c; s4 ^= c; c = t;
        s5 ^= c;                                       // counts <= 49 < 64
    }
    uint32_t qw[8];
    #pragma unroll
    for (int q = 0; q < 8; ++q) {
        uint32_t word = 0;
        #pragma unroll
        for (int r = 0; r < 4; ++r) {
            int j = q * 4 + r;
            uint32_t cnt = ((s0 >> j) & 1u)        | (((s1 >> j) & 1u) << 1)
                         | (((s2 >> j) & 1u) << 2) | (((s3 >> j) & 1u) << 3)
                         | (((s4 >> j) & 1u) << 4) | (((s5 >> j) & 1u) << 5);
            word |= cnt << (8 * r);
        }
        qw[q] = word;
    }
    uint4* o = (uint4*)(partial + (((size_t)pc * NB + b) * WPR + w) * 8);
    o[0] = make_uint4(qw[0], qw[1], qw[2], qw[3]);
    o[1] = make_uint4(qw[4], qw[5], qw[6], qw[7]);
}

// ---- phase 3 helper: one (b, word-slice) block task -------------------------
__device__ __forceinline__ void logits_task(int b, int ws, int tid,
                                            const uint32_t* __restrict__ partial,
                                            const float* __restrict__ cw,
                                            float* __restrict__ out,
                                            float (*red)[NC]) {
    float acc[NC];
    #pragma unroll
    for (int c = 0; c < NC; ++c) acc[c] = 0.0f;

    for (int t = tid; t < 40 * 8; t += BLK) {      // 40 words x 8 q per slice
        int wl = t >> 3, q = t & 7;
        int w  = ws * 40 + wl;
        int dbase = w * 32 + q * 4;
        if (w < WPR && dbase < D) {
            uint32_t aL = 0, aH = 0;
            #pragma unroll
            for (int pc = 0; pc < NPC; ++pc) {     // byte counts -> halfword sums
                uint32_t v = partial[(((size_t)pc * NB + b) * WPR + w) * 8 + q];
                aL += v & 0x00FF00FFu;
                aH += (v >> 8) & 0x00FF00FFu;
            }
            uint32_t c0 = aL & 0xFFFFu, c2 = aL >> 16;
            uint32_t c1 = aH & 0xFFFFu, c3 = aH >> 16;
            // enc = -1 iff cnt >= 392 (784 - 2*cnt <= 0): flip float sign bit
            uint32_t g0 = (c0 >= 392u) ? 0x80000000u : 0u;
            uint32_t g1 = (c1 >= 392u) ? 0x80000000u : 0u;
            uint32_t g2 = (c2 >= 392u) ? 0x80000000u : 0u;
            uint32_t g3 = (c3 >= 392u) ? 0x80000000u : 0u;
            #pragma unroll
            for (int c = 0; c < NC; ++c) {
                uint4 cv = *(const uint4*)(cw + (size_t)c * D + dbase);
                acc[c] += __uint_as_float(cv.x ^ g0) + __uint_as_float(cv.y ^ g1)
                        + __uint_as_float(cv.z ^ g2) + __uint_as_float(cv.w ^ g3);
            }
        }
    }
    int lane = tid & 63, wv = tid >> 6;
    #pragma unroll
    for (int c = 0; c < NC; ++c) {
        float v = acc[c];
        #pragma unroll
        for (int off = 32; off > 0; off >>= 1) v += __shfl_down(v, off, 64);
        if (lane == 0) red[wv][c] = v;
    }
    __syncthreads();
    if (tid < NC)
        atomicAdd(&out[b * NC + tid],
                  red[0][tid] + red[1][tid] + red[2][tid] + red[3][tid]);
}

// ---------------- fused cooperative kernel (conservative 512x256) ------------
__global__ __launch_bounds__(BLK, 2) void fused_kernel(
    const float* __restrict__ x, const float* __restrict__ pos,
    const float* __restrict__ lev, const float* __restrict__ cw,
    uint32_t* __restrict__ Lp, uint32_t* __restrict__ Pp,
    uint32_t* __restrict__ partial, float* __restrict__ out)
{
    cg::grid_group grid = cg::this_grid();
    const int tid = threadIdx.x;
    __shared__ float red[4][NC];

    for (int task = blockIdx.x * BLK + tid; task < NROWS * WPR; task += GRID * BLK)
        pack_task(task, lev, pos, Lp, Pp);
    if (blockIdx.x == 0)
        for (int i = tid; i < NB * NC; i += BLK) out[i] = 0.0f;
    grid.sync();

    {
        int wid  = blockIdx.x * 4 + (tid >> 6);
        int lane = tid & 63;
        for (int t = wid; t < NT2; t += GRID * 4) {
            int wb = t % 5;
            int bt = t / 5;
            int b  = bt & 63;
            int pc = bt >> 6;
            int vidx = 0;
            if (lane < PCL) {
                float xv = x[b * NPIX + pc * PCL + lane];
                int v = (int)rintf(xv * 255.0f);   // round-half-even == jnp.round
                v = v < 0 ? 0 : (v > 255 ? 255 : v);
                vidx = v * WPR;
            }
            count_task(b, pc, wb * 64 + lane, vidx, Lp, Pp, partial);
        }
    }
    grid.sync();

    logits_task(blockIdx.x >> 3, blockIdx.x & 7, tid, partial, cw, out, red);
}

// ---------------- fallback path: three ordinary kernels ----------------------
__global__ __launch_bounds__(BLK) void pack_fb(const float* __restrict__ lev,
                                               const float* __restrict__ pos,
                                               uint32_t* __restrict__ Lp,
                                               uint32_t* __restrict__ Pp,
                                               float* __restrict__ out) {
    for (int task = blockIdx.x * BLK + threadIdx.x; task < NROWS * WPR;
         task += GRID * BLK)
        pack_task(task, lev, pos, Lp, Pp);
    if (blockIdx.x == 0)
        for (int i = threadIdx.x; i < NB * NC; i += BLK) out[i] = 0.0f;
}

__global__ __launch_bounds__(64) void count_fb(const float* __restrict__ x,
                                               const uint32_t* __restrict__ Lp,
                                               const uint32_t* __restrict__ Pp,
                                               uint32_t* __restrict__ partial) {
    int lane = threadIdx.x;
    int b = blockIdx.y, pc = blockIdx.z;
    int vidx = 0;
    if (lane < PCL) {
        float xv = x[b * NPIX + pc * PCL + lane];
        int v = (int)rintf(xv * 255.0f);
        v = v < 0 ? 0 : (v > 255 ? 255 : v);
        vidx = v * WPR;
    }
    count_task(b, pc, blockIdx.x * 64 + lane, vidx, Lp, Pp, partial);
}

__global__ __launch_bounds__(BLK) void logits_fb(const uint32_t* __restrict__ partial,
                                                 const float* __restrict__ cw,
                                                 float* __restrict__ out) {
    __shared__ float red[4][NC];
    logits_task(blockIdx.x >> 3, blockIdx.x & 7, threadIdx.x, partial, cw, out, red);
}

extern "C" void kernel_launch(void* const* d_in, const int* in_sizes, int n_in,
                              void* d_out, int out_size, void* d_ws, size_t ws_size,
                              hipStream_t stream) {
    const float* x   = (const float*)d_in[0];   // [64, 28, 28]
    const float* pos = (const float*)d_in[1];   // [784, 10000]
    const float* lev = (const float*)d_in[2];   // [256, 10000]
    const float* cw  = (const float*)d_in[3];   // [10, 10000]
    float* out = (float*)d_out;                 // [64, 10] fp32

    uint32_t* Lp      = (uint32_t*)d_ws;        // 256*313 words
    uint32_t* Pp      = Lp + 256 * WPR;         // 784*313 words
    uint32_t* partial = Pp + NPIX * WPR;        // 16*64*313*8 words (10.3 MB)

    void* args[] = {(void*)&x, (void*)&pos, (void*)&lev, (void*)&cw,
                    (void*)&Lp, (void*)&Pp, (void*)&partial, (void*)&out};
    hipError_t err = hipLaunchCooperativeKernel((void*)fused_kernel, dim3(GRID),
                                                dim3(BLK), args, 0, stream);
    if (err != hipSuccess) {                    // identical math, ordinary launches
        pack_fb<<<GRID, BLK, 0, stream>>>(lev, pos, Lp, Pp, out);
        count_fb<<<dim3(5, NB, NPC), 64, 0, stream>>>(x, Lp, Pp, partial);
        logits_fb<<<GRID, BLK, 0, stream>>>(partial, cw, out);
    }
}

// Round 5
// 113.529 us; speedup vs baseline: 2.2261x; 2.2261x over previous
//
#include <hip/hip_runtime.h>
#include <stdint.h>

#define D      10000
#define WPR    313              // ceil(10000/32) words per hypervector row
#define NPIX   784
#define NB     64
#define NC     10
#define NROWS  (256 + NPIX)     // 1040 rows to pack
#define PCL    98               // pixels per wave-chunk (8 waves x 98 = 784)
#define BLK2   512              // 8 waves per fused block

// ---------------- K1: pack sign bits (bit=1 <=> value < 0) -------------------
// One 32-float word per thread via uint4 loads; block 0 zero-inits d_out.
__global__ __launch_bounds__(256) void pack_kernel(const float* __restrict__ lev,
                                                   const float* __restrict__ pos,
                                                   uint32_t* __restrict__ Lp,
                                                   uint32_t* __restrict__ Pp,
                                                   float* __restrict__ out) {
    if (blockIdx.x == 0)
        for (int i = threadIdx.x; i < NB * NC; i += 256) out[i] = 0.0f;

    int task = blockIdx.x * 256 + threadIdx.x;
    if (task >= NROWS * WPR) return;
    int row = task / WPR;
    int w   = task - row * WPR;
    const float* src; uint32_t* dst;
    if (row < 256) { src = lev + (size_t)row * D;         dst = Lp + row * WPR; }
    else           { src = pos + (size_t)(row - 256) * D; dst = Pp + (row - 256) * WPR; }
    const uint4* p4 = (const uint4*)(src + w * 32);
    uint32_t word = 0;
    int kmax = (w < WPR - 1) ? 8 : 4;          // last word: 16 valid floats
    for (int k = 0; k < kmax; ++k) {
        uint4 u = p4[k];
        word |= (u.x >> 31) << (4*k)     | (u.y >> 31) << (4*k + 1)
              | (u.z >> 31) << (4*k + 2) | (u.w >> 31) << (4*k + 3);
    }
    dst[w] = word;
}

// ---------------- K2: fused count + sign + classify GEMV ---------------------
// Block (wg, b): 64 words (2048 d) of batch b. Wave v counts sign mismatches of
// its 98-pixel chunk with a 7-slice bit-sliced ripple counter; waves combine
// byte-packed counts in LDS; then 512 threads = 64 words x 8 quads apply the
// sign to classify_weight and block-reduce 10 logits -> atomicAdd.
__global__ __launch_bounds__(BLK2, 2) void fused_kernel(const float* __restrict__ x,
                                                        const uint32_t* __restrict__ Lp,
                                                        const uint32_t* __restrict__ Pp,
                                                        const float* __restrict__ cw,
                                                        float* __restrict__ out) {
    const int tid  = threadIdx.x;
    const int lane = tid & 63;
    const int wv   = tid >> 6;                 // wave 0..7
    const int wg   = blockIdx.x;               // word group 0..4
    const int b    = blockIdx.y;

    __shared__ int      idxs[NPIX];            // level-row offsets (idx * WPR)
    __shared__ uint32_t qbuf[8][64][9];        // [wave][word-lane][q(+pad)] 18 KB
    __shared__ float    red[8][NC];

    for (int i = tid; i < NPIX; i += BLK2) {
        float xv = x[b * NPIX + i];
        int v = (int)rintf(xv * 255.0f);       // round-half-even == jnp.round
        v = v < 0 ? 0 : (v > 255 ? 255 : v);
        idxs[i] = v * WPR;
    }
    __syncthreads();

    int w = wg * 64 + lane;
    int p0 = wv * PCL;
    uint32_t s0 = 0, s1 = 0, s2 = 0, s3 = 0, s4 = 0, s5 = 0, s6 = 0;
    if (w < WPR) {
        const uint32_t* pp = Pp + (size_t)p0 * WPR + w;
        #pragma unroll 7
        for (int i = 0; i < PCL; ++i) {
            int ro = __builtin_amdgcn_readfirstlane(idxs[p0 + i]);  // uniform
            uint32_t c = Lp[ro + w] ^ pp[(size_t)i * WPR];
            uint32_t t;
            t = s0 & c; s0 ^= c; c = t;
            t = s1 & c; s1 ^= c; c = t;
            t = s2 & c; s2 ^= c; c = t;
            t = s3 & c; s3 ^= c; c = t;
            t = s4 & c; s4 ^= c; c = t;
            t = s5 & c; s5 ^= c; c = t;
            s6 ^= c;                           // counts <= 98 < 128
        }
    }
    #pragma unroll
    for (int q = 0; q < 8; ++q) {              // byte-pack 4 counts per q-word
        uint32_t word = 0;
        #pragma unroll
        for (int r = 0; r < 4; ++r) {
            int j = q * 4 + r;
            uint32_t cnt = ((s0 >> j) & 1u)        | (((s1 >> j) & 1u) << 1)
                         | (((s2 >> j) & 1u) << 2) | (((s3 >> j) & 1u) << 3)
                         | (((s4 >> j) & 1u) << 4) | (((s5 >> j) & 1u) << 5)
                         | (((s6 >> j) & 1u) << 6);
            word |= cnt << (8 * r);
        }
        qbuf[wv][lane][q] = word;              // lane stride 9 words: no conflicts
    }
    __syncthreads();

    // combine + sign + GEMV: thread = (word wl, quad q)
    float acc[NC];
    #pragma unroll
    for (int c = 0; c < NC; ++c) acc[c] = 0.0f;
    {
        int wl = tid >> 3, q = tid & 7;
        int w2 = wg * 64 + wl;
        int dbase = w2 * 32 + q * 4;
        if (w2 < WPR && dbase < D) {           // w=312: only q<4 valid
            uint32_t aL = 0, aH = 0;
            #pragma unroll
            for (int v = 0; v < 8; ++v) {      // byte counts -> halfword sums
                uint32_t u = qbuf[v][wl][q];
                aL += u & 0x00FF00FFu;
                aH += (u >> 8) & 0x00FF00FFu;
            }
            uint32_t c0 = aL & 0xFFFFu, c2 = aL >> 16;
            uint32_t c1 = aH & 0xFFFFu, c3 = aH >> 16;
            // enc = -1 iff cnt >= 392 (784 - 2*cnt <= 0): flip float sign bit
            uint32_t g0 = (c0 >= 392u) ? 0x80000000u : 0u;
            uint32_t g1 = (c1 >= 392u) ? 0x80000000u : 0u;
            uint32_t g2 = (c2 >= 392u) ? 0x80000000u : 0u;
            uint32_t g3 = (c3 >= 392u) ? 0x80000000u : 0u;
            #pragma unroll
            for (int c = 0; c < NC; ++c) {
                uint4 cv = *(const uint4*)(cw + (size_t)c * D + dbase);
                acc[c] += __uint_as_float(cv.x ^ g0) + __uint_as_float(cv.y ^ g1)
                        + __uint_as_float(cv.z ^ g2) + __uint_as_float(cv.w ^ g3);
            }
        }
    }
    #pragma unroll
    for (int c = 0; c < NC; ++c) {
        float v = acc[c];
        #pragma unroll
        for (int off = 32; off > 0; off >>= 1) v += __shfl_down(v, off, 64);
        if (lane == 0) red[wv][c] = v;
    }
    __syncthreads();
    if (tid < NC) {
        float s = 0.0f;
        #pragma unroll
        for (int v = 0; v < 8; ++v) s += red[v][tid];
        atomicAdd(&out[b * NC + tid], s);
    }
}

extern "C" void kernel_launch(void* const* d_in, const int* in_sizes, int n_in,
                              void* d_out, int out_size, void* d_ws, size_t ws_size,
                              hipStream_t stream) {
    const float* x   = (const float*)d_in[0];   // [64, 28, 28]
    const float* pos = (const float*)d_in[1];   // [784, 10000]
    const float* lev = (const float*)d_in[2];   // [256, 10000]
    const float* cw  = (const float*)d_in[3];   // [10, 10000]
    float* out = (float*)d_out;                 // [64, 10] fp32

    uint32_t* Lp = (uint32_t*)d_ws;             // 256*313 words (320 KB)
    uint32_t* Pp = Lp + 256 * WPR;              // 784*313 words (981 KB)

    pack_kernel<<<(NROWS * WPR + 255) / 256, 256, 0, stream>>>(lev, pos, Lp, Pp, out);
    fused_kernel<<<dim3(5, NB), BLK2, 0, stream>>>(x, Lp, Pp, cw, out);
}